// Round 2
// baseline (207.799 us; speedup 1.0000x reference)
//
#include <hip/hip_runtime.h>
#include <hip/hip_bf16.h>

// Key observation: the reference's einsums make attention a no-op.
//   energy = einsum('nasd,nbsd->nab')  -> (N,H,H), summed over s AND d
//   att    = softmax(energy, axis=2)   -> rows sum to 1
//   out    = einsum('nab,nhsd->nasd')  = (sum_b att[n,a,b]) * (sum_h v[n,h,s,d])
//                                      = sum_h v[n,h,s,d]          (indep. of a!)
// After the final reshape, out_flat[n,s,a*64+d] = vsum[n,s,d] for all heads a, so
//   result = (x @ WvSum) @ WoSum + bo
//     WvSum[k][d] = sum_h Wv[k][h*64+d]   (1024x64)
//     WoSum[d][e] = sum_h Wo[h*64+d][e]   (64x1024)
// Wq, Wk are entirely unused. Total: 4.2 GF fp32 + ~136 MB HBM traffic.

#define NROWS 16384  // BATCH*SEQ
#define EDIM 1024
#define DDIM 64
#define NHEADS 16

__global__ __launch_bounds__(256) void prep_kernel(
    const float* __restrict__ Wv, const float* __restrict__ Wo,
    float* __restrict__ WvS, float* __restrict__ WoS) {
  int i = blockIdx.x * 256 + threadIdx.x;  // 512 blocks -> 131072 threads
  if (i < 65536) {
    int k = i >> 6, d = i & 63;
    float s = 0.f;
#pragma unroll
    for (int h = 0; h < NHEADS; ++h) s += Wv[k * EDIM + h * DDIM + d];
    WvS[i] = s;  // row-major [k][d]
  } else {
    int j = i - 65536;
    int d = j >> 10, e = j & 1023;
    float s = 0.f;
#pragma unroll
    for (int h = 0; h < NHEADS; ++h) s += Wo[(h * DDIM + d) * EDIM + e];
    WoS[j] = s;  // row-major [d][e]
  }
}

// tmp[NROWS][64] = x[NROWS][1024] @ WvS[1024][64]
// 512 threads, 64-row tile, full N=64 in registers/LDS, K chunked by 64.
__global__ __launch_bounds__(512) void gemm_xv(
    const float* __restrict__ x, const float* __restrict__ WvS,
    float* __restrict__ tmp) {
  __shared__ float xs[64][64];  // [k][row]  (transposed x tile)
  __shared__ float ws[64][64];  // [k][col]
  const int tid = threadIdx.x;
  const int r0 = blockIdx.x * 64;
  const int tr = tid >> 4;  // 0..31 -> rows 2tr, 2tr+1
  const int tc = tid & 15;  // 0..15 -> cols 4tc..4tc+3
  float acc[2][4] = {{0.f, 0.f, 0.f, 0.f}, {0.f, 0.f, 0.f, 0.f}};
  for (int kb = 0; kb < EDIM; kb += 64) {
#pragma unroll
    for (int l = 0; l < 2; ++l) {
      int li = l * 512 + tid;  // 0..1023
      int row = li >> 4;       // 0..63
      int kc = (li & 15) << 2; // 0,4,..,60
      float4 v = *reinterpret_cast<const float4*>(&x[(r0 + row) * EDIM + kb + kc]);
      xs[kc + 0][row] = v.x;
      xs[kc + 1][row] = v.y;
      xs[kc + 2][row] = v.z;
      xs[kc + 3][row] = v.w;
      float4 w = *reinterpret_cast<const float4*>(&WvS[(kb + row) * DDIM + kc]);
      *reinterpret_cast<float4*>(&ws[row][kc]) = w;
    }
    __syncthreads();
#pragma unroll
    for (int k = 0; k < 64; ++k) {
      float2 a = *reinterpret_cast<const float2*>(&xs[k][tr << 1]);
      float4 b = *reinterpret_cast<const float4*>(&ws[k][tc << 2]);
      acc[0][0] += a.x * b.x; acc[0][1] += a.x * b.y;
      acc[0][2] += a.x * b.z; acc[0][3] += a.x * b.w;
      acc[1][0] += a.y * b.x; acc[1][1] += a.y * b.y;
      acc[1][2] += a.y * b.z; acc[1][3] += a.y * b.w;
    }
    __syncthreads();
  }
  int row = r0 + (tr << 1);
  *reinterpret_cast<float4*>(&tmp[row * DDIM + (tc << 2)]) =
      make_float4(acc[0][0], acc[0][1], acc[0][2], acc[0][3]);
  *reinterpret_cast<float4*>(&tmp[(row + 1) * DDIM + (tc << 2)]) =
      make_float4(acc[1][0], acc[1][1], acc[1][2], acc[1][3]);
}

// out[NROWS][1024] = tmp[NROWS][64] @ WoS[64][1024] + bo
// 512 threads; tile 32 rows x 128 cols; K=64 staged once (no k-chunk loop).
__global__ __launch_bounds__(512) void gemm_out(
    const float* __restrict__ tmp, const float* __restrict__ WoS,
    const float* __restrict__ bo, float* __restrict__ out) {
  __shared__ float ts[64][32];   // [k][row]
  __shared__ float ws[64][128];  // [k][col]  32 KB
  const int tid = threadIdx.x;
  const int rb = blockIdx.x >> 3;
  const int cb = blockIdx.x & 7;
  const int r0 = rb * 32, c0 = cb * 128;
  {
    int row = tid >> 4;          // 0..31
    int kc = (tid & 15) << 2;    // 0..60
    float4 v = *reinterpret_cast<const float4*>(&tmp[(r0 + row) * DDIM + kc]);
    ts[kc + 0][row] = v.x;
    ts[kc + 1][row] = v.y;
    ts[kc + 2][row] = v.z;
    ts[kc + 3][row] = v.w;
  }
#pragma unroll
  for (int l = 0; l < 4; ++l) {
    int li = l * 512 + tid;  // 0..2047
    int k = li >> 5;
    int c4 = (li & 31) << 2;
    *reinterpret_cast<float4*>(&ws[k][c4]) =
        *reinterpret_cast<const float4*>(&WoS[k * EDIM + c0 + c4]);
  }
  __syncthreads();
  const int tr = tid >> 5;  // 0..15 -> rows 2tr, 2tr+1
  const int tc = tid & 31;  // 0..31 -> cols 4tc..4tc+3
  float acc[2][4] = {{0.f, 0.f, 0.f, 0.f}, {0.f, 0.f, 0.f, 0.f}};
#pragma unroll
  for (int k = 0; k < 64; ++k) {
    float2 a = *reinterpret_cast<const float2*>(&ts[k][tr << 1]);
    float4 b = *reinterpret_cast<const float4*>(&ws[k][tc << 2]);
    acc[0][0] += a.x * b.x; acc[0][1] += a.x * b.y;
    acc[0][2] += a.x * b.z; acc[0][3] += a.x * b.w;
    acc[1][0] += a.y * b.x; acc[1][1] += a.y * b.y;
    acc[1][2] += a.y * b.z; acc[1][3] += a.y * b.w;
  }
  float4 bias = *reinterpret_cast<const float4*>(&bo[c0 + (tc << 2)]);
  int row = r0 + (tr << 1);
  int c = c0 + (tc << 2);
  *reinterpret_cast<float4*>(&out[row * EDIM + c]) =
      make_float4(acc[0][0] + bias.x, acc[0][1] + bias.y,
                  acc[0][2] + bias.z, acc[0][3] + bias.w);
  *reinterpret_cast<float4*>(&out[(row + 1) * EDIM + c]) =
      make_float4(acc[1][0] + bias.x, acc[1][1] + bias.y,
                  acc[1][2] + bias.z, acc[1][3] + bias.w);
}

extern "C" void kernel_launch(void* const* d_in, const int* in_sizes, int n_in,
                              void* d_out, int out_size, void* d_ws, size_t ws_size,
                              hipStream_t stream) {
  const float* x  = (const float*)d_in[0];
  // d_in[1] = Wq, d_in[2] = Wk: mathematically dead (softmax rows sum to 1).
  const float* Wv = (const float*)d_in[3];
  const float* Wo = (const float*)d_in[4];
  const float* bo = (const float*)d_in[5];
  float* out = (float*)d_out;

  // workspace layout: WvS (64K f32) | WoS (64K f32) | tmp (1M f32) = 4.5 MB
  float* WvS = (float*)d_ws;
  float* WoS = WvS + 65536;
  float* tmp = WoS + 65536;

  prep_kernel<<<512, 256, 0, stream>>>(Wv, Wo, WvS, WoS);
  gemm_xv<<<256, 512, 0, stream>>>(x, WvS, tmp);
  gemm_out<<<4096, 512, 0, stream>>>(tmp, WoS, bo, out);
}

// Round 3
// 153.043 us; speedup vs baseline: 1.3578x; 1.3578x over previous
//
#include <hip/hip_runtime.h>
#include <hip/hip_bf16.h>

// Math (validated by the fp32 round: passed, absmax 0.0625):
//   softmax rows sum to 1  =>  out = (x @ WvSum) @ WoSum + bo
//   WvSum[k][d] = sum_h Wv[k][h*64+d]   (1024x64);  WoSum[d][e] = sum_h Wo[h*64+d][e] (64x1024)
//   Wq, Wk dead.
// This round: fp32-VALU GEMM was measured LDS-throughput-bound (67.6us, VALUBusy 20%).
// Switch to bf16 MFMA with split-precision: a = ah + al (bf16 + bf16 residual),
// product = ah*bh + ah*bl + al*bh  (drop al*bl ~ 2^-18 rel). Error << tolerance.
// Both GEMMs become memory-bound (read x 64MB / write out 64MB ~ 10us each).

typedef __attribute__((ext_vector_type(8))) short bf16x8;   // 8 bf16 in 4 VGPRs
typedef __attribute__((ext_vector_type(4))) float f32x4;    // MFMA 16x16 accumulator

__device__ __forceinline__ unsigned short f2bf(float f) {   // fp32 -> bf16 RNE
  unsigned int u = __builtin_bit_cast(unsigned int, f);
  u += 0x7FFFu + ((u >> 16) & 1u);
  return (unsigned short)(u >> 16);
}
__device__ __forceinline__ float bf2f(unsigned short b) {
  unsigned int u = ((unsigned int)b) << 16;
  return __builtin_bit_cast(float, u);
}
__device__ __forceinline__ unsigned int pack2(unsigned short a, unsigned short b) {
  return (unsigned int)a | ((unsigned int)b << 16);
}
// split pair of floats into packed bf16 hi / lo words
__device__ __forceinline__ void split2(float a, float b, unsigned int& hi, unsigned int& lo) {
  unsigned short ha = f2bf(a), hb = f2bf(b);
  hi = pack2(ha, hb);
  lo = pack2(f2bf(a - bf2f(ha)), f2bf(b - bf2f(hb)));
}

// ---------------- prep: weight sums + bf16 splits (transposed for B-operand) --
// BvT[d][k] = WvSum[k][d]   as bf16 h/l, [64][1024]
// BoT[e][d] = WoSum[d][e]   as bf16 h/l, [1024][64]
__global__ __launch_bounds__(256) void prep(
    const float* __restrict__ Wv, const float* __restrict__ Wo,
    unsigned short* __restrict__ BvTh, unsigned short* __restrict__ BvTl,
    unsigned short* __restrict__ BoTh, unsigned short* __restrict__ BoTl) {
  const int b = blockIdx.x, t = threadIdx.x;
  if (b < 64) {           // WvSum rows k = b*16 .. +15, 16 threads/row
    const int k = b * 16 + (t >> 4);
    const int sub = (t & 15) << 2;     // d = sub..sub+3
    float s[4] = {0.f, 0.f, 0.f, 0.f};
#pragma unroll
    for (int h = 0; h < 16; ++h) {
      float4 v = *reinterpret_cast<const float4*>(&Wv[k * 1024 + h * 64 + sub]);
      s[0] += v.x; s[1] += v.y; s[2] += v.z; s[3] += v.w;
    }
#pragma unroll
    for (int j = 0; j < 4; ++j) {
      unsigned short h16 = f2bf(s[j]);
      BvTh[(sub + j) * 1024 + k] = h16;
      BvTl[(sub + j) * 1024 + k] = f2bf(s[j] - bf2f(h16));
    }
  } else {                // WoSum row d = b-64, thread covers e = 4t..4t+3
    const int d = b - 64;
    const int e0 = t << 2;
    float s[4] = {0.f, 0.f, 0.f, 0.f};
#pragma unroll
    for (int h = 0; h < 16; ++h) {
      float4 v = *reinterpret_cast<const float4*>(&Wo[(h * 64 + d) * 1024 + e0]);
      s[0] += v.x; s[1] += v.y; s[2] += v.z; s[3] += v.w;
    }
#pragma unroll
    for (int j = 0; j < 4; ++j) {
      unsigned short h16 = f2bf(s[j]);
      BoTh[(e0 + j) * 64 + d] = h16;
      BoTl[(e0 + j) * 64 + d] = f2bf(s[j] - bf2f(h16));
    }
  }
}

// ---------------- gemm1: tmp = x @ WvSum  (M=16384, N=64, K=1024) ------------
// tmp stored as bf16 splits for gemm2's A operand.
// BM=32, BK=64, 256 thr / 4 waves; wave-tile 16x32 (2 col-frags of 16x16x32).
// LDS rows padded to 72 bf16 (144 B) -> frag ds_read_b128 is 2-way = free.
__global__ __launch_bounds__(256) void gemm1(
    const float* __restrict__ x,
    const unsigned short* __restrict__ BvTh, const unsigned short* __restrict__ BvTl,
    unsigned short* __restrict__ tmph, unsigned short* __restrict__ tmpl) {
  __shared__ __align__(16) unsigned short Ah[2][32][72], Al[2][32][72];
  __shared__ __align__(16) unsigned short Bh[2][64][72], Bl[2][64][72];
  const int t = threadIdx.x;
  const int r0 = blockIdx.x * 32;
  const int w = t >> 6, l = t & 63;
  const int wr = (w >> 1) << 4;        // wave rows: 0 / 16
  const int wc = (w & 1) << 5;         // wave cols: 0 / 32
  const int lr = l & 15, lk = (l >> 4) << 3;
  // staging coords: x rows (coalesced float4 x2), B cols (coalesced 32B)
  const int srow = t >> 3, skg = (t & 7) << 3;
  const int bcol = t >> 2, bkg = (t & 3) << 4;

  f32x4 acc[2] = {};

  // prologue: stage chunk 0 into buf 0
  {
    const float* xp = &x[(r0 + srow) * 1024 + skg];
    float4 v0 = *reinterpret_cast<const float4*>(xp);
    float4 v1 = *reinterpret_cast<const float4*>(xp + 4);
    unsigned int h0, h1, h2, h3, lo0, lo1, lo2, lo3;
    split2(v0.x, v0.y, h0, lo0); split2(v0.z, v0.w, h1, lo1);
    split2(v1.x, v1.y, h2, lo2); split2(v1.z, v1.w, h3, lo3);
    *reinterpret_cast<uint4*>(&Ah[0][srow][skg]) = make_uint4(h0, h1, h2, h3);
    *reinterpret_cast<uint4*>(&Al[0][srow][skg]) = make_uint4(lo0, lo1, lo2, lo3);
    const unsigned short* pbh = &BvTh[bcol * 1024 + bkg];
    const unsigned short* pbl = &BvTl[bcol * 1024 + bkg];
    *reinterpret_cast<uint4*>(&Bh[0][bcol][bkg])     = *reinterpret_cast<const uint4*>(pbh);
    *reinterpret_cast<uint4*>(&Bh[0][bcol][bkg + 8]) = *reinterpret_cast<const uint4*>(pbh + 8);
    *reinterpret_cast<uint4*>(&Bl[0][bcol][bkg])     = *reinterpret_cast<const uint4*>(pbl);
    *reinterpret_cast<uint4*>(&Bl[0][bcol][bkg + 8]) = *reinterpret_cast<const uint4*>(pbl + 8);
  }

  for (int c = 0; c < 16; ++c) {
    const int buf = c & 1;
    __syncthreads();
    // T14: issue next chunk's global loads BEFORE compute (latency hides under MFMA)
    float4 v0, v1; uint4 nbh0, nbh1, nbl0, nbl1;
    const bool pf = (c + 1 < 16);
    if (pf) {
      const int kb = (c + 1) * 64;
      const float* xp = &x[(r0 + srow) * 1024 + kb + skg];
      v0 = *reinterpret_cast<const float4*>(xp);
      v1 = *reinterpret_cast<const float4*>(xp + 4);
      const unsigned short* pbh = &BvTh[bcol * 1024 + kb + bkg];
      const unsigned short* pbl = &BvTl[bcol * 1024 + kb + bkg];
      nbh0 = *reinterpret_cast<const uint4*>(pbh);
      nbh1 = *reinterpret_cast<const uint4*>(pbh + 8);
      nbl0 = *reinterpret_cast<const uint4*>(pbl);
      nbl1 = *reinterpret_cast<const uint4*>(pbl + 8);
    }
#pragma unroll
    for (int kk = 0; kk < 64; kk += 32) {
      bf16x8 ah = *reinterpret_cast<const bf16x8*>(&Ah[buf][wr + lr][kk + lk]);
      bf16x8 al = *reinterpret_cast<const bf16x8*>(&Al[buf][wr + lr][kk + lk]);
#pragma unroll
      for (int ct = 0; ct < 2; ++ct) {
        const int col = wc + (ct << 4) + lr;
        bf16x8 bh = *reinterpret_cast<const bf16x8*>(&Bh[buf][col][kk + lk]);
        bf16x8 bl = *reinterpret_cast<const bf16x8*>(&Bl[buf][col][kk + lk]);
        acc[ct] = __builtin_amdgcn_mfma_f32_16x16x32_bf16(ah, bh, acc[ct], 0, 0, 0);
        acc[ct] = __builtin_amdgcn_mfma_f32_16x16x32_bf16(ah, bl, acc[ct], 0, 0, 0);
        acc[ct] = __builtin_amdgcn_mfma_f32_16x16x32_bf16(al, bh, acc[ct], 0, 0, 0);
      }
    }
    if (pf) {
      const int nb = buf ^ 1;
      unsigned int h0, h1, h2, h3, lo0, lo1, lo2, lo3;
      split2(v0.x, v0.y, h0, lo0); split2(v0.z, v0.w, h1, lo1);
      split2(v1.x, v1.y, h2, lo2); split2(v1.z, v1.w, h3, lo3);
      *reinterpret_cast<uint4*>(&Ah[nb][srow][skg]) = make_uint4(h0, h1, h2, h3);
      *reinterpret_cast<uint4*>(&Al[nb][srow][skg]) = make_uint4(lo0, lo1, lo2, lo3);
      *reinterpret_cast<uint4*>(&Bh[nb][bcol][bkg])     = nbh0;
      *reinterpret_cast<uint4*>(&Bh[nb][bcol][bkg + 8]) = nbh1;
      *reinterpret_cast<uint4*>(&Bl[nb][bcol][bkg])     = nbl0;
      *reinterpret_cast<uint4*>(&Bl[nb][bcol][bkg + 8]) = nbl1;
    }
  }

  // epilogue: C/D layout col = l&15, row = (l>>4)*4 + j  [m89-verified]
#pragma unroll
  for (int ct = 0; ct < 2; ++ct) {
    const int col = wc + (ct << 4) + lr;
#pragma unroll
    for (int j = 0; j < 4; ++j) {
      const int row = r0 + wr + ((l >> 4) << 2) + j;
      float v = acc[ct][j];
      unsigned short h = f2bf(v);
      tmph[row * 64 + col] = h;
      tmpl[row * 64 + col] = f2bf(v - bf2f(h));
    }
  }
}

// ---------------- gemm2: out = tmp @ WoSum + bo  (M=16384, N=1024, K=64) -----
// BM=64, BN=128, 256 thr / 4 waves; wave-tile 16x128 (8 col-frags). K staged once.
__global__ __launch_bounds__(256) void gemm2(
    const unsigned short* __restrict__ tmph, const unsigned short* __restrict__ tmpl,
    const unsigned short* __restrict__ BoTh, const unsigned short* __restrict__ BoTl,
    const float* __restrict__ bo, float* __restrict__ out) {
  __shared__ __align__(16) unsigned short Ah[64][72], Al[64][72];
  __shared__ __align__(16) unsigned short Bh[128][72], Bl[128][72];
  const int t = threadIdx.x;
  const int mb = blockIdx.x >> 3, nb = blockIdx.x & 7;
  const int r0 = mb << 6, c0 = nb << 7;
  {
    const int ar = t >> 2, akg = (t & 3) << 4;
    const unsigned short* p = &tmph[(r0 + ar) * 64 + akg];
    *reinterpret_cast<uint4*>(&Ah[ar][akg])     = *reinterpret_cast<const uint4*>(p);
    *reinterpret_cast<uint4*>(&Ah[ar][akg + 8]) = *reinterpret_cast<const uint4*>(p + 8);
    p = &tmpl[(r0 + ar) * 64 + akg];
    *reinterpret_cast<uint4*>(&Al[ar][akg])     = *reinterpret_cast<const uint4*>(p);
    *reinterpret_cast<uint4*>(&Al[ar][akg + 8]) = *reinterpret_cast<const uint4*>(p + 8);
    const int bc = t >> 1, bkg = (t & 1) << 5;
    p = &BoTh[(c0 + bc) * 64 + bkg];
#pragma unroll
    for (int j = 0; j < 4; ++j)
      *reinterpret_cast<uint4*>(&Bh[bc][bkg + j * 8]) = *reinterpret_cast<const uint4*>(p + j * 8);
    p = &BoTl[(c0 + bc) * 64 + bkg];
#pragma unroll
    for (int j = 0; j < 4; ++j)
      *reinterpret_cast<uint4*>(&Bl[bc][bkg + j * 8]) = *reinterpret_cast<const uint4*>(p + j * 8);
  }
  __syncthreads();
  const int w = t >> 6, l = t & 63;
  const int wr = w << 4;
  const int lr = l & 15, lk = (l >> 4) << 3;
  f32x4 acc[8] = {};
#pragma unroll
  for (int kk = 0; kk < 64; kk += 32) {
    bf16x8 ah = *reinterpret_cast<const bf16x8*>(&Ah[wr + lr][kk + lk]);
    bf16x8 al = *reinterpret_cast<const bf16x8*>(&Al[wr + lr][kk + lk]);
#pragma unroll
    for (int ct = 0; ct < 8; ++ct) {
      bf16x8 bh = *reinterpret_cast<const bf16x8*>(&Bh[(ct << 4) + lr][kk + lk]);
      bf16x8 bl = *reinterpret_cast<const bf16x8*>(&Bl[(ct << 4) + lr][kk + lk]);
      acc[ct] = __builtin_amdgcn_mfma_f32_16x16x32_bf16(ah, bh, acc[ct], 0, 0, 0);
      acc[ct] = __builtin_amdgcn_mfma_f32_16x16x32_bf16(ah, bl, acc[ct], 0, 0, 0);
      acc[ct] = __builtin_amdgcn_mfma_f32_16x16x32_bf16(al, bh, acc[ct], 0, 0, 0);
    }
  }
#pragma unroll
  for (int ct = 0; ct < 8; ++ct) {
    const int col = c0 + (ct << 4) + lr;
    const float bv = bo[col];
#pragma unroll
    for (int j = 0; j < 4; ++j) {
      const int row = r0 + wr + ((l >> 4) << 2) + j;
      out[row * 1024 + col] = acc[ct][j] + bv;
    }
  }
}

extern "C" void kernel_launch(void* const* d_in, const int* in_sizes, int n_in,
                              void* d_out, int out_size, void* d_ws, size_t ws_size,
                              hipStream_t stream) {
  const float* x  = (const float*)d_in[0];
  // d_in[1] = Wq, d_in[2] = Wk: mathematically dead (softmax rows sum to 1).
  const float* Wv = (const float*)d_in[3];
  const float* Wo = (const float*)d_in[4];
  const float* bo = (const float*)d_in[5];
  float* out = (float*)d_out;

  // ws layout (ushort): BvTh|BvTl (64x1024 ea) | BoTh|BoTl (1024x64 ea) | tmph|tmpl (16384x64 ea)
  unsigned short* BvTh = (unsigned short*)d_ws;
  unsigned short* BvTl = BvTh + 65536;
  unsigned short* BoTh = BvTl + 65536;
  unsigned short* BoTl = BoTh + 65536;
  unsigned short* tmph = BoTl + 65536;
  unsigned short* tmpl = tmph + 1048576;   // total 4.5 MB

  prep<<<128, 256, 0, stream>>>(Wv, Wo, BvTh, BvTl, BoTh, BoTl);
  gemm1<<<512, 256, 0, stream>>>(x, BvTh, BvTl, tmph, tmpl);
  gemm2<<<2048, 256, 0, stream>>>(tmph, tmpl, BoTh, BoTl, bo, out);
}

// Round 4
// 152.702 us; speedup vs baseline: 1.3608x; 1.0022x over previous
//
#include <hip/hip_runtime.h>
#include <hip/hip_bf16.h>

// Math (validated: rounds 2-3 passed): softmax rows sum to 1 =>
//   out = (x @ WvSum) @ WoSum + bo,  Wq/Wk dead.
//   WvSum[k][d] = sum_h Wv[k][h*64+d]  (1024x64)
//   WoSum[d][e] = sum_h Wo[h*64+d][e]  (64x1024)
// Numerics: split-bf16 (a=ah+al), product ah*bh + ah*bl + al*bh (round-3: absmax 0.125, passed).
// This round: B operands pre-arranged in per-lane MFMA fragment order by prep
// (HK pre-swizzled-global pattern) -> both GEMMs load B L2->registers directly;
// no B LDS staging at all. gemm2 reuses A-frags across 32 col-frags and spreads
// stores through the loop.

typedef __attribute__((ext_vector_type(8))) short bf16x8;
typedef __attribute__((ext_vector_type(4))) float f32x4;

__device__ __forceinline__ unsigned short f2bf(float f) {  // fp32 -> bf16 RNE
  unsigned int u = __builtin_bit_cast(unsigned int, f);
  u += 0x7FFFu + ((u >> 16) & 1u);
  return (unsigned short)(u >> 16);
}
__device__ __forceinline__ float bf2f(unsigned short b) {
  unsigned int u = ((unsigned int)b) << 16;
  return __builtin_bit_cast(float, u);
}
__device__ __forceinline__ unsigned int pack2(unsigned short a, unsigned short b) {
  return (unsigned int)a | ((unsigned int)b << 16);
}
__device__ __forceinline__ void split2(float a, float b, unsigned int& hi, unsigned int& lo) {
  unsigned short ha = f2bf(a), hb = f2bf(b);
  hi = pack2(ha, hb);
  lo = pack2(f2bf(a - bf2f(ha)), f2bf(b - bf2f(hb)));
}
__device__ __forceinline__ bf16x8 asbf(uint4 u) { return __builtin_bit_cast(bf16x8, u); }

// ---------------- prep: weight sums -> B operands in MFMA-frag order ---------
// BvF frag layout (uint4 index): ((s*4 + ctg)*2 + hl)*64 + lane
//   holds WvSum[k = s*32 + (lane>>4)*8 + j][col = ctg*16 + (lane&15)], j=0..7
// BoF frag layout (uint4 index): ((ctg2*2 + kk)*2 + hl)*64 + lane
//   holds WoSum[k = kk*32 + (lane>>4)*8 + j][e = ctg2*16 + (lane&15)], j=0..7
__global__ __launch_bounds__(256) void prep(const float* __restrict__ Wv,
                                            const float* __restrict__ Wo,
                                            unsigned short* __restrict__ BvF,
                                            unsigned short* __restrict__ BoF) {
  const int b = blockIdx.x, t = threadIdx.x;
  const int l = t & 63, lr = l & 15, lk = (l >> 4) << 3;
  if (b < 32) {                 // Bv frags, k-slice s = b
    const int s = b, ctg = t >> 6;        // ctg == wave id (uniform per wave)
    const int d = (ctg << 4) + lr;
    const int k0 = (s << 5) + lk;
    float sum[8] = {};
#pragma unroll
    for (int h = 0; h < 16; ++h)
#pragma unroll
      for (int j = 0; j < 8; ++j)
        sum[j] += Wv[(k0 + j) * 1024 + h * 64 + d];
    unsigned short hh[8], ll[8];
#pragma unroll
    for (int j = 0; j < 8; ++j) {
      hh[j] = f2bf(sum[j]);
      ll[j] = f2bf(sum[j] - bf2f(hh[j]));
    }
    const int base = ((s * 4 + ctg) * 2) * 64 + l;   // uint4 index, hl=0
    uint4 uh = make_uint4(pack2(hh[0], hh[1]), pack2(hh[2], hh[3]),
                          pack2(hh[4], hh[5]), pack2(hh[6], hh[7]));
    uint4 ul = make_uint4(pack2(ll[0], ll[1]), pack2(ll[2], ll[3]),
                          pack2(ll[4], ll[5]), pack2(ll[6], ll[7]));
    ((uint4*)BvF)[base] = uh;
    ((uint4*)BvF)[base + 64] = ul;                   // hl=1
  } else {                      // Bo frags, col-frag ctg2 = b-32
    const int ctg2 = b - 32;
    const int kk = t >> 7, jh = (t >> 6) & 1;
    const int e = (ctg2 << 4) + lr;
    const int kb = (kk << 5) + lk + (jh << 2);
    float sum[4] = {};
#pragma unroll
    for (int h = 0; h < 16; ++h)
#pragma unroll
      for (int j = 0; j < 4; ++j)
        sum[j] += Wo[(h * 64 + kb + j) * 1024 + e];
    unsigned short hh[4], ll[4];
#pragma unroll
    for (int j = 0; j < 4; ++j) {
      hh[j] = f2bf(sum[j]);
      ll[j] = f2bf(sum[j] - bf2f(hh[j]));
    }
    // uint2 index: frag row (8 ushorts) = 2 x uint2; hl stride = 128 uint2
    const int base = ((((ctg2 * 2 + kk) * 2) * 64 + l) << 1) + jh;
    ((uint2*)BoF)[base] = make_uint2(pack2(hh[0], hh[1]), pack2(hh[2], hh[3]));
    ((uint2*)BoF)[base + 128] = make_uint2(pack2(ll[0], ll[1]), pack2(ll[2], ll[3]));
  }
}

// ---------------- gemm1: tmp = x @ WvSum  (M=16384, N=64, K=1024) ------------
// BM=32, BK=64, 256 thr / 4 waves (wave-tile 16x32), grid 512 -> 2 blocks/CU.
// Only x goes through LDS (h/l split, dbuf); Bv frags stream L2->regs ping-pong.
__global__ __launch_bounds__(256) void gemm1(const float* __restrict__ x,
                                             const unsigned short* __restrict__ BvF,
                                             unsigned short* __restrict__ tmph,
                                             unsigned short* __restrict__ tmpl) {
  __shared__ unsigned short Ah[2][32][72], Al[2][32][72];   // 18.4 KB
  const int t = threadIdx.x;
  const int r0 = blockIdx.x << 5;
  const int w = t >> 6, l = t & 63;
  const int wr = (w >> 1) << 4;        // wave rows 0/16
  const int ctgb = (w & 1) << 1;       // wave col-frag base: 0/2 (cols 0/32)
  const int lr = l & 15, lk = (l >> 4) << 3;
  const int srow = t >> 3, skg = (t & 7) << 3;
  const float* xp = &x[(r0 + srow) * 1024 + skg];
  const uint4* bp = (const uint4*)BvF;

  float4 xr[2][2];
  uint4 br[2][8];
  f32x4 acc[2] = {};

  // prologue: x(0)->xr[0], x(1)->xr[1], B(0)->br[0]; write x(0) to LDS buf0
  xr[0][0] = *(const float4*)(xp);
  xr[0][1] = *(const float4*)(xp + 4);
  xr[1][0] = *(const float4*)(xp + 64);
  xr[1][1] = *(const float4*)(xp + 68);
#pragma unroll
  for (int kk = 0; kk < 2; ++kk)
#pragma unroll
    for (int ct = 0; ct < 2; ++ct)
#pragma unroll
      for (int hl = 0; hl < 2; ++hl)
        br[0][(kk * 2 + ct) * 2 + hl] =
            bp[((kk * 4 + ctgb + ct) * 2 + hl) * 64 + l];
  {
    unsigned int h0, h1, h2, h3, q0, q1, q2, q3;
    split2(xr[0][0].x, xr[0][0].y, h0, q0);
    split2(xr[0][0].z, xr[0][0].w, h1, q1);
    split2(xr[0][1].x, xr[0][1].y, h2, q2);
    split2(xr[0][1].z, xr[0][1].w, h3, q3);
    *(uint4*)&Ah[0][srow][skg] = make_uint4(h0, h1, h2, h3);
    *(uint4*)&Al[0][srow][skg] = make_uint4(q0, q1, q2, q3);
  }

#pragma unroll
  for (int c = 0; c < 16; ++c) {
    const int buf = c & 1;
    if (c + 2 < 16) {                  // depth-2 x prefetch into freed bank
      const float* xq = xp + (c + 2) * 64;
      xr[buf][0] = *(const float4*)(xq);
      xr[buf][1] = *(const float4*)(xq + 4);
    }
    if (c + 1 < 16) {                  // depth-1 B-frag prefetch (L2)
#pragma unroll
      for (int kk = 0; kk < 2; ++kk)
#pragma unroll
        for (int ct = 0; ct < 2; ++ct)
#pragma unroll
          for (int hl = 0; hl < 2; ++hl)
            br[buf ^ 1][(kk * 2 + ct) * 2 + hl] =
                bp[((((c + 1) * 2 + kk) * 4 + ctgb + ct) * 2 + hl) * 64 + l];
    }
    __syncthreads();
#pragma unroll
    for (int kk = 0; kk < 2; ++kk) {
      bf16x8 ah = *(const bf16x8*)&Ah[buf][wr + lr][kk * 32 + lk];
      bf16x8 al = *(const bf16x8*)&Al[buf][wr + lr][kk * 32 + lk];
#pragma unroll
      for (int ct = 0; ct < 2; ++ct) {
        bf16x8 bh = asbf(br[buf][(kk * 2 + ct) * 2 + 0]);
        bf16x8 bl = asbf(br[buf][(kk * 2 + ct) * 2 + 1]);
        acc[ct] = __builtin_amdgcn_mfma_f32_16x16x32_bf16(ah, bh, acc[ct], 0, 0, 0);
        acc[ct] = __builtin_amdgcn_mfma_f32_16x16x32_bf16(ah, bl, acc[ct], 0, 0, 0);
        acc[ct] = __builtin_amdgcn_mfma_f32_16x16x32_bf16(al, bh, acc[ct], 0, 0, 0);
      }
    }
    if (c + 1 < 16) {                  // split + LDS-write x(c+1) -> other buf
      unsigned int h0, h1, h2, h3, q0, q1, q2, q3;
      float4 a0 = xr[buf ^ 1][0], a1 = xr[buf ^ 1][1];
      split2(a0.x, a0.y, h0, q0);
      split2(a0.z, a0.w, h1, q1);
      split2(a1.x, a1.y, h2, q2);
      split2(a1.z, a1.w, h3, q3);
      *(uint4*)&Ah[buf ^ 1][srow][skg] = make_uint4(h0, h1, h2, h3);
      *(uint4*)&Al[buf ^ 1][srow][skg] = make_uint4(q0, q1, q2, q3);
    }
  }

  // epilogue: acc -> LDS bounce (coalesced 16B tmp stores)
  __syncthreads();
  {
    unsigned short* sh = &Ah[0][0][0];
    unsigned short* sl = &Al[0][0][0];
#pragma unroll
    for (int ct = 0; ct < 2; ++ct) {
      const int col = ((ctgb + ct) << 4) + lr;
#pragma unroll
      for (int j = 0; j < 4; ++j) {
        const int r = wr + ((l >> 4) << 2) + j;
        float v = acc[ct][j];
        unsigned short h = f2bf(v);
        sh[r * 72 + col] = h;
        sl[r * 72 + col] = f2bf(v - bf2f(h));
      }
    }
  }
  __syncthreads();
  {
    const int row = t >> 3, kg = (t & 7) << 3;
    uint4 vh = *(const uint4*)&Ah[0][row][kg];
    uint4 vl = *(const uint4*)&Al[0][row][kg];
    *(uint4*)&tmph[(r0 + row) * 64 + kg] = vh;
    *(uint4*)&tmpl[(r0 + row) * 64 + kg] = vl;
  }
}

// ---------------- gemm2: out = tmp @ WoSum + bo  (M=16384, N=1024, K=64) -----
// Block = 64 rows x 512 cols, grid 512 -> 2 blocks/CU, single resident wave of
// blocks. A-frags held in 4 regs reused across 32 col-frags; Bo frags stream
// L2->regs ping-pong; stores spread through the loop (write BW overlaps MFMA).
__global__ __launch_bounds__(256) void gemm2(const unsigned short* __restrict__ tmph,
                                             const unsigned short* __restrict__ tmpl,
                                             const unsigned short* __restrict__ BoF,
                                             const float* __restrict__ bo,
                                             float* __restrict__ out) {
  __shared__ unsigned short Ah[64][72], Al[64][72];   // 18.4 KB
  const int t = threadIdx.x;
  const int mb = blockIdx.x >> 1, nb = blockIdx.x & 1;
  const int r0 = mb << 6, c0 = nb << 9;
  const int l = t & 63, lr = l & 15, lk = (l >> 4) << 3;
  const int wr = (t >> 6) << 4;
  const uint4* bp = (const uint4*)BoF;

  {  // stage tmp h/l (coalesced 32B/thread)
    const int row = t >> 2, kg = (t & 3) << 4;
    const uint4* ph = (const uint4*)&tmph[(r0 + row) * 64 + kg];
    uint4 a0 = ph[0], a1 = ph[1];
    const uint4* pl4 = (const uint4*)&tmpl[(r0 + row) * 64 + kg];
    uint4 b0 = pl4[0], b1 = pl4[1];
    *(uint4*)&Ah[row][kg] = a0;
    *(uint4*)&Ah[row][kg + 8] = a1;
    *(uint4*)&Al[row][kg] = b0;
    *(uint4*)&Al[row][kg + 8] = b1;
  }
  uint4 brg[2][4];
  float bvr[2];
#pragma unroll
  for (int kk = 0; kk < 2; ++kk)
#pragma unroll
    for (int hl = 0; hl < 2; ++hl)
      brg[0][kk * 2 + hl] = bp[(((nb * 32) * 2 + kk) * 2 + hl) * 64 + l];
  bvr[0] = bo[c0 + lr];
  __syncthreads();

  bf16x8 afh[2], afl[2];
#pragma unroll
  for (int kk = 0; kk < 2; ++kk) {
    afh[kk] = *(const bf16x8*)&Ah[wr + lr][kk * 32 + lk];
    afl[kk] = *(const bf16x8*)&Al[wr + lr][kk * 32 + lk];
  }

#pragma unroll
  for (int ct = 0; ct < 32; ++ct) {
    if (ct + 1 < 32) {
#pragma unroll
      for (int kk = 0; kk < 2; ++kk)
#pragma unroll
        for (int hl = 0; hl < 2; ++hl)
          brg[(ct + 1) & 1][kk * 2 + hl] =
              bp[(((nb * 32 + ct + 1) * 2 + kk) * 2 + hl) * 64 + l];
      bvr[(ct + 1) & 1] = bo[c0 + ((ct + 1) << 4) + lr];
    }
    f32x4 a = {};
#pragma unroll
    for (int kk = 0; kk < 2; ++kk) {
      bf16x8 bh = asbf(brg[ct & 1][kk * 2 + 0]);
      bf16x8 bl = asbf(brg[ct & 1][kk * 2 + 1]);
      a = __builtin_amdgcn_mfma_f32_16x16x32_bf16(afh[kk], bh, a, 0, 0, 0);
      a = __builtin_amdgcn_mfma_f32_16x16x32_bf16(afh[kk], bl, a, 0, 0, 0);
      a = __builtin_amdgcn_mfma_f32_16x16x32_bf16(afl[kk], bh, a, 0, 0, 0);
    }
    const int col = c0 + (ct << 4) + lr;
    const float bv = bvr[ct & 1];
#pragma unroll
    for (int j = 0; j < 4; ++j)
      out[(r0 + wr + ((l >> 4) << 2) + j) * 1024 + col] = a[j] + bv;
  }
}

extern "C" void kernel_launch(void* const* d_in, const int* in_sizes, int n_in,
                              void* d_out, int out_size, void* d_ws, size_t ws_size,
                              hipStream_t stream) {
  const float* x = (const float*)d_in[0];
  // d_in[1] = Wq, d_in[2] = Wk: mathematically dead (softmax rows sum to 1).
  const float* Wv = (const float*)d_in[3];
  const float* Wo = (const float*)d_in[4];
  const float* bo = (const float*)d_in[5];
  float* out = (float*)d_out;

  // ws (ushort): BvF 128K | BoF 128K | tmph 1M | tmpl 1M  (~4.7 MB)
  unsigned short* BvF = (unsigned short*)d_ws;
  unsigned short* BoF = BvF + 131072;
  unsigned short* tmph = BoF + 131072;
  unsigned short* tmpl = tmph + 1048576;

  prep<<<96, 256, 0, stream>>>(Wv, Wo, BvF, BoF);
  gemm1<<<512, 256, 0, stream>>>(x, BvF, tmph, tmpl);
  gemm2<<<512, 256, 0, stream>>>(tmph, tmpl, BoF, bo, out);
}